// Round 11
// baseline (115.193 us; speedup 1.0000x reference)
//
#include <hip/hip_runtime.h>
#include <hip/hip_bf16.h>

#define SEQ 2048
#define NH 16
#define DH 64
#define EMB 1024

typedef __bf16 bf16;
typedef __attribute__((ext_vector_type(8))) __bf16 bf16x8;
typedef __attribute__((ext_vector_type(4))) __bf16 bf16x4;
typedef __attribute__((ext_vector_type(4))) float f32x4;
typedef __attribute__((ext_vector_type(4))) unsigned int u32x4;
typedef unsigned long long u64;

// workspace layout (bytes)
#define OFF_MQK  0                         // 64*64 bf16      = 8 KB
#define OFF_WO2  8192                      // 1024*1024 bf16  = 2 MB (fragment order)
#define OFF_K2   (8192 + 2097152)          // [N][H][32 kt][8KB frag tiles] = 8 MB
#define OFF_VT   (OFF_K2 + 8388608)        // [N][H][32 kt][8KB frag tiles] = 8 MB
#define OFF_A2   (OFF_VT + 8388608)        // [N][L][1024] bf16  = 8 MB
#define OFF_MB   (OFF_A2 + 8388608)        // mbt[N][32 kt][2048 q] u64 = 1 MB

#define LOG2E 1.44269504088896340736f

__device__ __forceinline__ f32x4 mfma16(bf16x8 a, bf16x8 b, f32x4 c) {
  return __builtin_amdgcn_mfma_f32_16x16x32_bf16(a, b, c, 0, 0, 0);
}

#define GL16(g, l)                                                            \
  __builtin_amdgcn_global_load_lds(                                           \
      (const __attribute__((address_space(1))) void*)(g),                     \
      (__attribute__((address_space(3))) void*)(l), 16, 0, 0)

__device__ __forceinline__ unsigned pack_bf16(float p0, float p1) {
  unsigned short b0 = __builtin_bit_cast(unsigned short, (bf16)p0);
  unsigned short b1 = __builtin_bit_cast(unsigned short, (bf16)p1);
  return (unsigned)b0 | ((unsigned)b1 << 16);
}

// ---------------- P0: Mqk = (Wq^T Wk) * log2(e)/8, to bf16 (16 blocks) -----
__global__ __launch_bounds__(256) void prep0(const float* __restrict__ Wq,
                                             const float* __restrict__ Wk,
                                             bf16* __restrict__ mqk) {
  __shared__ float wq[64 * 64];
  __shared__ float wk[64 * 64];
  int tid = threadIdx.x, b = blockIdx.x;
  for (int i = tid; i < 4096; i += 256) { wq[i] = Wq[i]; wk[i] = Wk[i]; }
  __syncthreads();
  int d1 = b * 4 + (tid >> 6), d2 = tid & 63;
  float s = 0.f;
#pragma unroll
  for (int e = 0; e < 64; ++e) s += wq[e * 64 + d1] * wk[e * 64 + d2];
  mqk[d1 * 64 + d2] = (bf16)(s * 0.125f * LOG2E);
}

// ---------------- fused prep: prep1(MFMA) | proj_k2 | vtrans | maskpack ----
// grid: [0,256) prep1, [256,1280) proj_k2, [1280,2304) vtrans, rest maskpack
__global__ __launch_bounds__(256) void prep_fused(
    const float* __restrict__ Wo, const float* __restrict__ Wv,
    const float* __restrict__ keys, const bf16* __restrict__ mqk,
    const float* __restrict__ values, const int* __restrict__ mask,
    bf16* __restrict__ wo2f, bf16* __restrict__ k2f, bf16* __restrict__ vtf,
    u64* __restrict__ mbt) {
  __shared__ __align__(16) float smem[5184];  // 20.7 KB shared by branches
  int blk = blockIdx.x;
  int tid = threadIdx.x;

  if (blk < 256) {
    // ---- prep1 (MFMA): Wo2[e][h64+dp] = sum_d Wo[e][h64+d]*Wv[d][dp]
    int h = blk >> 4, eg = blk & 15;
    int wave = tid >> 6, lane = tid & 63;
    int g = lane >> 4, c = lane & 15;
    float (*wvT)[65] = (float(*)[65])smem;
    for (int i = tid; i < 4096; i += 256) {
      int d = i >> 6, dp = i & 63;
      wvT[dp][d] = Wv[i];
    }
    __syncthreads();
    bf16x8 am[4][2];
#pragma unroll
    for (int t = 0; t < 4; ++t)
#pragma unroll
      for (int s = 0; s < 2; ++s) {
        bf16x8 v;
#pragma unroll
        for (int i = 0; i < 8; ++i)
          v[i] = (bf16)wvT[16 * t + c][32 * s + 8 * g + i];
        am[t][s] = v;
      }
    int e = eg * 64 + wave * 16 + c;
    const float* worow = Wo + (size_t)e * 1024 + h * DH;
    bf16x8 bfr[2];
#pragma unroll
    for (int s = 0; s < 2; ++s) {
      f32x4 x0 = *(const f32x4*)(worow + 32 * s + 8 * g);
      f32x4 x1 = *(const f32x4*)(worow + 32 * s + 8 * g + 4);
      bf16x8 t;
#pragma unroll
      for (int i = 0; i < 4; ++i) { t[i] = (bf16)x0[i]; t[4 + i] = (bf16)x1[i]; }
      bfr[s] = t;
    }
    char* tb = (char*)wo2f + (size_t)(eg * 32 + h * 2) * 4096 + wave * 1024;
#pragma unroll
    for (int t = 0; t < 4; ++t) {
      f32x4 a = {0.f, 0.f, 0.f, 0.f};
      a = mfma16(am[t][0], bfr[0], a);
      a = mfma16(am[t][1], bfr[1], a);
      bf16x4 w;
#pragma unroll
      for (int r = 0; r < 4; ++r) w[r] = (bf16)a[r];
      char* dst = tb + (t >> 1) * 4096 +
                  ((2 * (t & 1) + (g >> 1)) * 16 + c) * 16 + 8 * (g & 1);
      *(bf16x4*)dst = w;
    }
  } else if (blk < 1280) {
    // ---- proj_k2: K2' = k_raw @ Mqk^T, fragment order
    int b = blk - 256;
    int lt = b & 31, h = (b >> 5) & 15, n = b >> 9;
    int wave = tid >> 6, lane = tid & 63;
    int g = lane >> 4, c = lane & 15;
    bf16x8 am[4][2];
#pragma unroll
    for (int t = 0; t < 4; ++t)
#pragma unroll
      for (int s = 0; s < 2; ++s)
        am[t][s] = *(const bf16x8*)(mqk + (16 * t + c) * 64 + 32 * s + 8 * g);
    int l = lt * 64 + wave * 16 + c;
    const float* krow = keys + ((size_t)(n * SEQ + l)) * EMB + h * DH;
    bf16x8 bfr[2];
#pragma unroll
    for (int s = 0; s < 2; ++s) {
      f32x4 x0 = *(const f32x4*)(krow + 32 * s + 8 * g);
      f32x4 x1 = *(const f32x4*)(krow + 32 * s + 8 * g + 4);
      bf16x8 t;
#pragma unroll
      for (int i = 0; i < 4; ++i) { t[i] = (bf16)x0[i]; t[4 + i] = (bf16)x1[i]; }
      bfr[s] = t;
    }
    char* tb = (char*)k2f + (size_t)((n * NH + h) * 32 + lt) * 8192 + wave * 2048;
#pragma unroll
    for (int t = 0; t < 4; ++t) {
      f32x4 a = {0.f, 0.f, 0.f, 0.f};
      a = mfma16(am[t][0], bfr[0], a);
      a = mfma16(am[t][1], bfr[1], a);
      bf16x4 w;
#pragma unroll
      for (int r = 0; r < 4; ++r) w[r] = (bf16)a[r];
      char* dst = tb + (t >> 1) * 1024 +
                  ((2 * (t & 1) + (g >> 1)) * 16 + c) * 16 + 8 * (g & 1);
      *(bf16x4*)dst = w;
    }
  } else if (blk < 2304) {
    // ---- vtrans: V^T fragment order
    int b = blk - 1280;
    int lt = b & 31, h = (b >> 5) & 15, n = b >> 9;
    float (*lds)[65] = (float(*)[65])smem;
    {
      int r = tid >> 2, cg = (tid & 3) * 16;
      const float* vrow =
          values + ((size_t)(n * SEQ + lt * 64 + r)) * EMB + h * DH + cg;
#pragma unroll
      for (int j = 0; j < 16; j += 4) {
        f32x4 x = *(const f32x4*)(vrow + j);
        lds[r][cg + j + 0] = x[0];
        lds[r][cg + j + 1] = x[1];
        lds[r][cg + j + 2] = x[2];
        lds[r][cg + j + 3] = x[3];
      }
    }
    __syncthreads();
    {
      int d = tid >> 2, q16 = tid & 3, lb = q16 * 16;
      bf16x8 w0, w1;
#pragma unroll
      for (int j = 0; j < 8; ++j) w0[j] = (bf16)lds[lb + j][d];
#pragma unroll
      for (int j = 0; j < 8; ++j) w1[j] = (bf16)lds[lb + 8 + j][d];
      int dt = d >> 4, cc = d & 15;
      int s = q16 >> 1, gg = 2 * (q16 & 1);
      char* base = (char*)vtf + (size_t)((n * NH + h) * 32 + lt) * 8192 +
                   (2 * dt + s) * 1024;
      *(bf16x8*)(base + (gg * 16 + cc) * 16) = w0;
      *(bf16x8*)(base + ((gg + 1) * 16 + cc) * 16) = w1;
    }
  } else {
    // ---- maskpack (grid-stride), TRANSPOSED: mbt[n][kw][q]
    int base = (blk - 2304) * 4 + (tid >> 6);
    int lane = tid & 63;
#pragma unroll
    for (int i = 0; i < 16; ++i) {
      int w = base + i * 8192;  // w = (n*2048 + q)*32 + kw
      int v = mask[(size_t)w * 64 + lane];
      u64 bbits = __ballot(v != 0);
      int kw = w & 31, q = (w >> 5) & 2047, nn = w >> 16;
      if (lane == 0) mbt[((size_t)nn * 32 + kw) * 2048 + q] = bbits;
    }
  }
}

// ---------------- F: flash attention — 1 wave/block, reg K + dbuf V --------
// R6 core (70.6us) + V reg double-buffer & mask prefetch (spare VGPR: grid-
// limited 2 waves/SIMD -> up to 256 regs free). K-split (R7-R9) regressed;
// do not re-add. (64,2) bound: cap 256 regs, no spill (R7 lesson).
__global__ __launch_bounds__(64, 2) void attn(const float* __restrict__ qraw,
                                              const bf16* __restrict__ k2f,
                                              const bf16* __restrict__ vtf,
                                              const u64* __restrict__ mbt,
                                              bf16* __restrict__ a2) {
  // bijective XCD swizzle: 2048 blocks, 256 per XCD -> ~4 (n,h) per XCD L2
  int swz = ((blockIdx.x & 7) << 8) | (blockIdx.x >> 3);
  int qt = swz & 63, h = (swz >> 6) & 15, n = swz >> 10;  // qt: 32-row tile
  int lane = threadIdx.x, g = lane >> 4, c = lane & 15;

  __shared__ u64 lutm[16];  // nibble -> packed-pair AND masks
  if (lane < 16) {
    unsigned a = (lane & 1 ? 0xFFFFu : 0u) | (lane & 2 ? 0xFFFF0000u : 0u);
    unsigned b = (lane & 4 ? 0xFFFFu : 0u) | (lane & 8 ? 0xFFFF0000u : 0u);
    lutm[lane] = (u64)a | ((u64)b << 32);
  }
  __syncthreads();

  // Q fragments: per qi, lane holds q = qt*32 + qi*16 + c, d = 32s+8g+i
  bf16x8 qf[2][2];
#pragma unroll
  for (int qi = 0; qi < 2; ++qi) {
    int q = qt * 32 + qi * 16 + c;
    const float* qrow = qraw + ((size_t)(n * SEQ + q)) * EMB + h * DH;
#pragma unroll
    for (int s = 0; s < 2; ++s) {
      f32x4 x0 = *(const f32x4*)(qrow + 32 * s + 8 * g);
      f32x4 x1 = *(const f32x4*)(qrow + 32 * s + 8 * g + 4);
      bf16x8 t;
#pragma unroll
      for (int i = 0; i < 4; ++i) { t[i] = (bf16)x0[i]; t[4 + i] = (bf16)x1[i]; }
      qf[qi][s] = t;
    }
  }
  const char* kp = (const char*)k2f + (size_t)(n * NH + h) * 32 * 8192 + lane * 16;
  const char* vp = (const char*)vtf + (size_t)(n * NH + h) * 32 * 8192 + lane * 16;
  const u64* mq = mbt + (size_t)n * 32 * 2048 + qt * 32 + c;  // +kt*2048+qi*16

  // prologue: K(0), VA=V(0), masks(0)
  bf16x8 K[8], VA[8], VB[8];
#pragma unroll
  for (int j = 0; j < 8; ++j) K[j] = *(const bf16x8*)(kp + j * 1024);
#pragma unroll
  for (int j = 0; j < 8; ++j) VA[j] = *(const bf16x8*)(vp + j * 1024);
  u64 mw0c = mq[0], mw1c = mq[16];

  f32x4 oacc[2][4];
#pragma unroll
  for (int qi = 0; qi < 2; ++qi)
#pragma unroll
    for (int dt = 0; dt < 4; ++dt) oacc[qi][dt] = (f32x4){0.f, 0.f, 0.f, 0.f};
  float mrun[2] = {-1e30f, -1e30f}, lrun[2] = {0.f, 0.f};
  bf16x8 ones;
#pragma unroll
  for (int i = 0; i < 8; ++i) ones[i] = (bf16)1.0f;
  int sh0 = 4 * g, sh1 = sh0 + 16;
  int srcA = ((g & 1) << 5) | c;
  int srcB = srcA + 16;
  bool hi2 = (g >> 1) != 0;

  // one k-tile: QK with K regs; prefetch K/V(next)+masks(next); softmax; PV(VC)
#define TILE(KT, VC, VN)                                                      \
  {                                                                           \
    f32x4 sacc[2][4];                                                         \
    _Pragma("unroll") for (int t = 0; t < 4; ++t) {                           \
      bf16x8 k0 = K[2 * t], k1 = K[2 * t + 1];                                \
      _Pragma("unroll") for (int qi = 0; qi < 2; ++qi) {                      \
        f32x4 a = {0.f, 0.f, 0.f, 0.f};                                       \
        a = mfma16(k0, qf[qi][0], a);                                         \
        a = mfma16(k1, qf[qi][1], a);                                         \
        sacc[qi][t] = a;                                                      \
      }                                                                       \
    }                                                                         \
    /* prefetch next tile: K regs dead after QK; VN free; full-tile window */ \
    _Pragma("unroll") for (int j = 0; j < 8; ++j)                             \
        K[j] = *(const bf16x8*)(kp + (size_t)((KT) + 1) * 8192 + j * 1024);   \
    _Pragma("unroll") for (int j = 0; j < 8; ++j)                             \
        VN[j] = *(const bf16x8*)(vp + (size_t)((KT) + 1) * 8192 + j * 1024);  \
    int ktn = (KT) < 31 ? (KT) + 1 : 31;                                      \
    u64 mw0n = mq[ktn * 2048];                                                \
    u64 mw1n = mq[ktn * 2048 + 16];                                           \
    float tmax[2];                                                            \
    _Pragma("unroll") for (int qi = 0; qi < 2; ++qi) {                        \
      float x0 = sacc[qi][0][0], x1 = sacc[qi][0][1], x2 = sacc[qi][0][2],    \
            x3 = sacc[qi][0][3], x4 = sacc[qi][1][0], x5 = sacc[qi][1][1],    \
            x6 = sacc[qi][1][2], x7 = sacc[qi][1][3], x8 = sacc[qi][2][0],    \
            x9 = sacc[qi][2][1], xa = sacc[qi][2][2], xb = sacc[qi][2][3],    \
            xc = sacc[qi][3][0], xd = sacc[qi][3][1], xe = sacc[qi][3][2],    \
            xf = sacc[qi][3][3];                                              \
      float t0 = fmaxf(fmaxf(x0, x1), x2);                                    \
      float t1 = fmaxf(fmaxf(x3, x4), x5);                                    \
      float t2 = fmaxf(fmaxf(x6, x7), x8);                                    \
      float t3 = fmaxf(fmaxf(x9, xa), xb);                                    \
      float t4 = fmaxf(fmaxf(xc, xd), xe);                                    \
      float m = fmaxf(fmaxf(fmaxf(t0, t1), t2), fmaxf(fmaxf(t3, t4), xf));    \
      m = fmaxf(m, __shfl_xor(m, 16));                                        \
      m = fmaxf(m, __shfl_xor(m, 32));                                        \
      tmax[qi] = m;                                                           \
    }                                                                         \
    bool needs = (tmax[0] > mrun[0] + 8.f) || (tmax[1] > mrun[1] + 8.f);      \
    if (__any(needs)) {                                                       \
      _Pragma("unroll") for (int qi = 0; qi < 2; ++qi) {                      \
        float mnew = fmaxf(mrun[qi], tmax[qi]);                               \
        float scl = __builtin_amdgcn_exp2f(mrun[qi] - mnew);                  \
        lrun[qi] *= scl;                                                      \
        _Pragma("unroll") for (int dt = 0; dt < 4; ++dt) {                    \
          oacc[qi][dt][0] *= scl; oacc[qi][dt][1] *= scl;                     \
          oacc[qi][dt][2] *= scl; oacc[qi][dt][3] *= scl;                     \
        }                                                                     \
        mrun[qi] = mnew;                                                      \
      }                                                                       \
    }                                                                         \
    unsigned wpk[2][4][2];                                                    \
    u64 mwa[2] = {mw0c, mw1c};                                                \
    _Pragma("unroll") for (int qi = 0; qi < 2; ++qi) {                        \
      unsigned mlo = (unsigned)mwa[qi], mhi = (unsigned)(mwa[qi] >> 32);      \
      u64 L[4];                                                               \
      L[0] = lutm[(mlo >> sh0) & 15];                                         \
      L[1] = lutm[(mlo >> sh1) & 15];                                         \
      L[2] = lutm[(mhi >> sh0) & 15];                                         \
      L[3] = lutm[(mhi >> sh1) & 15];                                         \
      float mr = mrun[qi];                                                    \
      _Pragma("unroll") for (int t = 0; t < 4; ++t) {                         \
        float p0 = __builtin_amdgcn_exp2f(sacc[qi][t][0] - mr);               \
        float p1 = __builtin_amdgcn_exp2f(sacc[qi][t][1] - mr);               \
        float p2 = __builtin_amdgcn_exp2f(sacc[qi][t][2] - mr);               \
        float p3 = __builtin_amdgcn_exp2f(sacc[qi][t][3] - mr);               \
        wpk[qi][t][0] = pack_bf16(p0, p1) & (unsigned)L[t];                   \
        wpk[qi][t][1] = pack_bf16(p2, p3) & (unsigned)(L[t] >> 32);           \
      }                                                                       \
    }                                                                         \
    bf16x8 pf[2][2];                                                          \
    _Pragma("unroll") for (int qi = 0; qi < 2; ++qi)                          \
        _Pragma("unroll") for (int s = 0; s < 2; ++s) {                       \
      unsigned ta0 = (unsigned)__shfl((int)wpk[qi][2 * s][0], srcA);          \
      unsigned ta1 = (unsigned)__shfl((int)wpk[qi][2 * s][1], srcA);          \
      unsigned tb0 = (unsigned)__shfl((int)wpk[qi][2 * s + 1][0], srcA);      \
      unsigned tb1 = (unsigned)__shfl((int)wpk[qi][2 * s + 1][1], srcA);      \
      unsigned ua0 = (unsigned)__shfl((int)wpk[qi][2 * s][0], srcB);          \
      unsigned ua1 = (unsigned)__shfl((int)wpk[qi][2 * s][1], srcB);          \
      unsigned ub0 = (unsigned)__shfl((int)wpk[qi][2 * s + 1][0], srcB);      \
      unsigned ub1 = (unsigned)__shfl((int)wpk[qi][2 * s + 1][1], srcB);      \
      u32x4 f;                                                                \
      f[0] = hi2 ? tb0 : ta0;                                                 \
      f[1] = hi2 ? tb1 : ta1;                                                 \
      f[2] = hi2 ? ub0 : ua0;                                                 \
      f[3] = hi2 ? ub1 : ua1;                                                 \
      pf[qi][s] = __builtin_bit_cast(bf16x8, f);                              \
    }                                                                         \
    f32x4 pacc[2];                                                            \
    _Pragma("unroll") for (int qi = 0; qi < 2; ++qi) {                        \
      f32x4 a = {0.f, 0.f, 0.f, 0.f};                                         \
      a = mfma16(ones, pf[qi][0], a);                                         \
      a = mfma16(ones, pf[qi][1], a);                                         \
      pacc[qi] = a;                                                           \
    }                                                                         \
    _Pragma("unroll") for (int dt = 0; dt < 4; ++dt)                          \
        _Pragma("unroll") for (int s = 0; s < 2; ++s) {                       \
      bf16x8 vf = VC[2 * dt + s];                                             \
      _Pragma("unroll") for (int qi = 0; qi < 2; ++qi)                        \
          oacc[qi][dt] = mfma16(vf, pf[qi][s], oacc[qi][dt]);                 \
    }                                                                         \
    _Pragma("unroll") for (int qi = 0; qi < 2; ++qi) lrun[qi] += pacc[qi][0]; \
    mw0c = mw0n;                                                              \
    mw1c = mw1n;                                                              \
  }

  for (int kt2 = 0; kt2 < 16; ++kt2) {
    TILE(2 * kt2, VA, VB);
    TILE(2 * kt2 + 1, VB, VA);
  }
#undef TILE

#pragma unroll
  for (int qi = 0; qi < 2; ++qi) {
    float inv = 1.0f / lrun[qi];
    int q = qt * 32 + qi * 16 + c;
    bf16* orow = a2 + ((size_t)(n * SEQ + q)) * EMB + h * DH;
#pragma unroll
    for (int dt = 0; dt < 4; ++dt) {
      bf16x4 w2;
#pragma unroll
      for (int r = 0; r < 4; ++r) w2[r] = (bf16)(oacc[qi][dt][r] * inv);
      *(bf16x4*)(orow + 16 * dt + 4 * g) = w2;
    }
  }
}

// ---------------- G: out = a2 · Wo2^T + bo (LDS-staged, BK=128) ------------
__global__ __launch_bounds__(256) void out_gemm(const bf16* __restrict__ a2,
                                                const bf16* __restrict__ wo2f,
                                                const float* __restrict__ bo,
                                                float* __restrict__ out) {
  int blk = blockIdx.x;  // mt*16 + et
  int et = blk & 15, mt = blk >> 4;
  int tid = threadIdx.x, wave = tid >> 6, lane = tid & 63;
  int g = lane >> 4, c = lane & 15;
  int m = mt * 64 + wave * 16 + c;
  const bf16* arow = a2 + (size_t)m * EMB + 8 * g;

  __shared__ bf16 wbuf[2][8192];  // 2 x 16KB (four 4KB kc-chunks each)
  const char* wtile = (const char*)wo2f + (size_t)et * 32 * 4096;
  int lofs = lane * 16, wofs = wave * 1024;

#define STAGEW(J, BUF)                                                        \
  {                                                                           \
    const char* src_ = wtile + (size_t)(J) * 16384 + wofs + lofs;             \
    char* dst_ = (char*)&wbuf[BUF][0] + wofs;                                 \
    GL16(src_, dst_);                                                         \
    GL16(src_ + 4096, dst_ + 4096);                                           \
    GL16(src_ + 8192, dst_ + 8192);                                           \
    GL16(src_ + 12288, dst_ + 12288);                                         \
  }

  STAGEW(0, 0);
  bf16x8 bn[4];
#pragma unroll
  for (int q = 0; q < 4; ++q) bn[q] = *(const bf16x8*)(arow + q * 32);
  __syncthreads();

  f32x4 acc[4];
#pragma unroll
  for (int t = 0; t < 4; ++t) acc[t] = (f32x4){0.f, 0.f, 0.f, 0.f};

  for (int j = 0; j < 8; ++j) {
    int cur = j & 1;
    bf16x8 b0 = bn[0], b1 = bn[1], b2 = bn[2], b3 = bn[3];
    if (j < 7) {
      STAGEW(j + 1, cur ^ 1);
#pragma unroll
      for (int q = 0; q < 4; ++q)
        bn[q] = *(const bf16x8*)(arow + (j + 1) * 128 + q * 32);
    }
    const bf16* wb = &wbuf[cur][0];
#pragma unroll
    for (int t = 0; t < 4; ++t)
      acc[t] = mfma16(*(const bf16x8*)(wb + t * 512 + lane * 8), b0, acc[t]);
#pragma unroll
    for (int t = 0; t < 4; ++t)
      acc[t] =
          mfma16(*(const bf16x8*)(wb + 2048 + t * 512 + lane * 8), b1, acc[t]);
#pragma unroll
    for (int t = 0; t < 4; ++t)
      acc[t] =
          mfma16(*(const bf16x8*)(wb + 4096 + t * 512 + lane * 8), b2, acc[t]);
#pragma unroll
    for (int t = 0; t < 4; ++t)
      acc[t] =
          mfma16(*(const bf16x8*)(wb + 6144 + t * 512 + lane * 8), b3, acc[t]);
    __syncthreads();
  }
#pragma unroll
  for (int t = 0; t < 4; ++t) {
    int e = et * 64 + 16 * t + 4 * g;
    f32x4 b = *(const f32x4*)(bo + e);
    f32x4 w;
#pragma unroll
    for (int r = 0; r < 4; ++r) w[r] = acc[t][r] + b[r];
    *(f32x4*)(out + (size_t)m * EMB + e) = w;
  }
}

extern "C" void kernel_launch(void* const* d_in, const int* in_sizes, int n_in,
                              void* d_out, int out_size, void* d_ws, size_t ws_size,
                              hipStream_t stream) {
  const float* values = (const float*)d_in[0];
  const float* keys   = (const float*)d_in[1];
  const float* query  = (const float*)d_in[2];
  const int*   mask   = (const int*)d_in[3];
  const float* Wv     = (const float*)d_in[4];
  const float* Wk     = (const float*)d_in[5];
  const float* Wq     = (const float*)d_in[6];
  const float* Wo     = (const float*)d_in[7];
  const float* bo     = (const float*)d_in[8];

  char* ws = (char*)d_ws;
  bf16* mqk  = (bf16*)(ws + OFF_MQK);
  bf16* wo2f = (bf16*)(ws + OFF_WO2);
  bf16* k2f  = (bf16*)(ws + OFF_K2);
  bf16* vtf  = (bf16*)(ws + OFF_VT);
  bf16* a2   = (bf16*)(ws + OFF_A2);
  u64*  mbt  = (u64*)(ws + OFF_MB);

  prep0<<<16, 256, 0, stream>>>(Wq, Wk, mqk);
  prep_fused<<<4352, 256, 0, stream>>>(Wo, Wv, keys, mqk, values, mask,
                                       wo2f, k2f, vtf, mbt);
  attn<<<2048, 64, 0, stream>>>(query, k2f, vtf, mbt, a2);
  out_gemm<<<1024, 256, 0, stream>>>(a2, wo2f, bo, (float*)d_out);
}

// Round 12
// 109.574 us; speedup vs baseline: 1.0513x; 1.0513x over previous
//
#include <hip/hip_runtime.h>
#include <hip/hip_bf16.h>

#define SEQ 2048
#define NH 16
#define DH 64
#define EMB 1024

typedef __bf16 bf16;
typedef __attribute__((ext_vector_type(8))) __bf16 bf16x8;
typedef __attribute__((ext_vector_type(4))) __bf16 bf16x4;
typedef __attribute__((ext_vector_type(4))) float f32x4;
typedef __attribute__((ext_vector_type(4))) unsigned int u32x4;
typedef unsigned long long u64;

// workspace layout (bytes)
#define OFF_MQK  0                         // 64*64 bf16      = 8 KB
#define OFF_WO2  8192                      // 1024*1024 bf16  = 2 MB (fragment order)
#define OFF_K2   (8192 + 2097152)          // [N][H][32 kt][8KB frag tiles] = 8 MB
#define OFF_VT   (OFF_K2 + 8388608)        // [N][H][32 kt][8KB frag tiles] = 8 MB
#define OFF_A2   (OFF_VT + 8388608)        // [N][L][1024] bf16  = 8 MB
#define OFF_MB   (OFF_A2 + 8388608)        // mbt[N][32 kt][2048 q] u64 = 1 MB

#define LOG2E 1.44269504088896340736f

__device__ __forceinline__ f32x4 mfma16(bf16x8 a, bf16x8 b, f32x4 c) {
  return __builtin_amdgcn_mfma_f32_16x16x32_bf16(a, b, c, 0, 0, 0);
}

#define GL16(g, l)                                                            \
  __builtin_amdgcn_global_load_lds(                                           \
      (const __attribute__((address_space(1))) void*)(g),                     \
      (__attribute__((address_space(3))) void*)(l), 16, 0, 0)

__device__ __forceinline__ unsigned pack_bf16(float p0, float p1) {
  unsigned short b0 = __builtin_bit_cast(unsigned short, (bf16)p0);
  unsigned short b1 = __builtin_bit_cast(unsigned short, (bf16)p1);
  return (unsigned)b0 | ((unsigned)b1 << 16);
}

// ---------------- P0: Mqk = (Wq^T Wk) * log2(e)/8, to bf16 (16 blocks) -----
__global__ __launch_bounds__(256) void prep0(const float* __restrict__ Wq,
                                             const float* __restrict__ Wk,
                                             bf16* __restrict__ mqk) {
  __shared__ float wq[64 * 64];
  __shared__ float wk[64 * 64];
  int tid = threadIdx.x, b = blockIdx.x;
  for (int i = tid; i < 4096; i += 256) { wq[i] = Wq[i]; wk[i] = Wk[i]; }
  __syncthreads();
  int d1 = b * 4 + (tid >> 6), d2 = tid & 63;
  float s = 0.f;
#pragma unroll
  for (int e = 0; e < 64; ++e) s += wq[e * 64 + d1] * wk[e * 64 + d2];
  mqk[d1 * 64 + d2] = (bf16)(s * 0.125f * LOG2E);
}

// ---------------- fused prep: prep1(MFMA) | proj_k2 | vtrans | maskpack ----
// grid: [0,256) prep1, [256,1280) proj_k2, [1280,2304) vtrans, rest maskpack
__global__ __launch_bounds__(256) void prep_fused(
    const float* __restrict__ Wo, const float* __restrict__ Wv,
    const float* __restrict__ keys, const bf16* __restrict__ mqk,
    const float* __restrict__ values, const int* __restrict__ mask,
    bf16* __restrict__ wo2f, bf16* __restrict__ k2f, bf16* __restrict__ vtf,
    u64* __restrict__ mbt) {
  __shared__ __align__(16) float smem[5184];  // 20.7 KB shared by branches
  int blk = blockIdx.x;
  int tid = threadIdx.x;

  if (blk < 256) {
    // ---- prep1 (MFMA): Wo2[e][h64+dp] = sum_d Wo[e][h64+d]*Wv[d][dp]
    int h = blk >> 4, eg = blk & 15;
    int wave = tid >> 6, lane = tid & 63;
    int g = lane >> 4, c = lane & 15;
    float (*wvT)[65] = (float(*)[65])smem;
    for (int i = tid; i < 4096; i += 256) {
      int d = i >> 6, dp = i & 63;
      wvT[dp][d] = Wv[i];
    }
    __syncthreads();
    bf16x8 am[4][2];
#pragma unroll
    for (int t = 0; t < 4; ++t)
#pragma unroll
      for (int s = 0; s < 2; ++s) {
        bf16x8 v;
#pragma unroll
        for (int i = 0; i < 8; ++i)
          v[i] = (bf16)wvT[16 * t + c][32 * s + 8 * g + i];
        am[t][s] = v;
      }
    int e = eg * 64 + wave * 16 + c;
    const float* worow = Wo + (size_t)e * 1024 + h * DH;
    bf16x8 bfr[2];
#pragma unroll
    for (int s = 0; s < 2; ++s) {
      f32x4 x0 = *(const f32x4*)(worow + 32 * s + 8 * g);
      f32x4 x1 = *(const f32x4*)(worow + 32 * s + 8 * g + 4);
      bf16x8 t;
#pragma unroll
      for (int i = 0; i < 4; ++i) { t[i] = (bf16)x0[i]; t[4 + i] = (bf16)x1[i]; }
      bfr[s] = t;
    }
    char* tb = (char*)wo2f + (size_t)(eg * 32 + h * 2) * 4096 + wave * 1024;
#pragma unroll
    for (int t = 0; t < 4; ++t) {
      f32x4 a = {0.f, 0.f, 0.f, 0.f};
      a = mfma16(am[t][0], bfr[0], a);
      a = mfma16(am[t][1], bfr[1], a);
      bf16x4 w;
#pragma unroll
      for (int r = 0; r < 4; ++r) w[r] = (bf16)a[r];
      char* dst = tb + (t >> 1) * 4096 +
                  ((2 * (t & 1) + (g >> 1)) * 16 + c) * 16 + 8 * (g & 1);
      *(bf16x4*)dst = w;
    }
  } else if (blk < 1280) {
    // ---- proj_k2: K2' = k_raw @ Mqk^T, fragment order
    int b = blk - 256;
    int lt = b & 31, h = (b >> 5) & 15, n = b >> 9;
    int wave = tid >> 6, lane = tid & 63;
    int g = lane >> 4, c = lane & 15;
    bf16x8 am[4][2];
#pragma unroll
    for (int t = 0; t < 4; ++t)
#pragma unroll
      for (int s = 0; s < 2; ++s)
        am[t][s] = *(const bf16x8*)(mqk + (16 * t + c) * 64 + 32 * s + 8 * g);
    int l = lt * 64 + wave * 16 + c;
    const float* krow = keys + ((size_t)(n * SEQ + l)) * EMB + h * DH;
    bf16x8 bfr[2];
#pragma unroll
    for (int s = 0; s < 2; ++s) {
      f32x4 x0 = *(const f32x4*)(krow + 32 * s + 8 * g);
      f32x4 x1 = *(const f32x4*)(krow + 32 * s + 8 * g + 4);
      bf16x8 t;
#pragma unroll
      for (int i = 0; i < 4; ++i) { t[i] = (bf16)x0[i]; t[4 + i] = (bf16)x1[i]; }
      bfr[s] = t;
    }
    char* tb = (char*)k2f + (size_t)((n * NH + h) * 32 + lt) * 8192 + wave * 2048;
#pragma unroll
    for (int t = 0; t < 4; ++t) {
      f32x4 a = {0.f, 0.f, 0.f, 0.f};
      a = mfma16(am[t][0], bfr[0], a);
      a = mfma16(am[t][1], bfr[1], a);
      bf16x4 w;
#pragma unroll
      for (int r = 0; r < 4; ++r) w[r] = (bf16)a[r];
      char* dst = tb + (t >> 1) * 1024 +
                  ((2 * (t & 1) + (g >> 1)) * 16 + c) * 16 + 8 * (g & 1);
      *(bf16x4*)dst = w;
    }
  } else if (blk < 2304) {
    // ---- vtrans: V^T fragment order
    int b = blk - 1280;
    int lt = b & 31, h = (b >> 5) & 15, n = b >> 9;
    float (*lds)[65] = (float(*)[65])smem;
    {
      int r = tid >> 2, cg = (tid & 3) * 16;
      const float* vrow =
          values + ((size_t)(n * SEQ + lt * 64 + r)) * EMB + h * DH + cg;
#pragma unroll
      for (int j = 0; j < 16; j += 4) {
        f32x4 x = *(const f32x4*)(vrow + j);
        lds[r][cg + j + 0] = x[0];
        lds[r][cg + j + 1] = x[1];
        lds[r][cg + j + 2] = x[2];
        lds[r][cg + j + 3] = x[3];
      }
    }
    __syncthreads();
    {
      int d = tid >> 2, q16 = tid & 3, lb = q16 * 16;
      bf16x8 w0, w1;
#pragma unroll
      for (int j = 0; j < 8; ++j) w0[j] = (bf16)lds[lb + j][d];
#pragma unroll
      for (int j = 0; j < 8; ++j) w1[j] = (bf16)lds[lb + 8 + j][d];
      int dt = d >> 4, cc = d & 15;
      int s = q16 >> 1, gg = 2 * (q16 & 1);
      char* base = (char*)vtf + (size_t)((n * NH + h) * 32 + lt) * 8192 +
                   (2 * dt + s) * 1024;
      *(bf16x8*)(base + (gg * 16 + cc) * 16) = w0;
      *(bf16x8*)(base + ((gg + 1) * 16 + cc) * 16) = w1;
    }
  } else {
    // ---- maskpack (grid-stride), TRANSPOSED: mbt[n][kw][q]
    int base = (blk - 2304) * 4 + (tid >> 6);
    int lane = tid & 63;
#pragma unroll
    for (int i = 0; i < 16; ++i) {
      int w = base + i * 8192;  // w = (n*2048 + q)*32 + kw
      int v = mask[(size_t)w * 64 + lane];
      u64 bbits = __ballot(v != 0);
      int kw = w & 31, q = (w >> 5) & 2047, nn = w >> 16;
      if (lane == 0) mbt[((size_t)nn * 32 + kw) * 2048 + q] = bbits;
    }
  }
}

// ---------------- F: flash attention — 1 wave/block, all-register K/V ------
// R6/R10 structure FROZEN at ~70.6us. Proven dead ends: K-split (R7-R9,
// merge overhead > occupancy gain), deeper V/mask prefetch (R11, null —
// structure is at its overlap limit, not waitcnt-exposed). (64,2): cap 256
// regs; (64,4)-style tightening spills (R7 lesson).
__global__ __launch_bounds__(64, 2) void attn(const float* __restrict__ qraw,
                                              const bf16* __restrict__ k2f,
                                              const bf16* __restrict__ vtf,
                                              const u64* __restrict__ mbt,
                                              bf16* __restrict__ a2) {
  // bijective XCD swizzle: 2048 blocks, 256 per XCD -> ~4 (n,h) per XCD L2
  int swz = ((blockIdx.x & 7) << 8) | (blockIdx.x >> 3);
  int qt = swz & 63, h = (swz >> 6) & 15, n = swz >> 10;  // qt: 32-row tile
  int lane = threadIdx.x, g = lane >> 4, c = lane & 15;

  __shared__ u64 lutm[16];  // nibble -> packed-pair AND masks
  if (lane < 16) {
    unsigned a = (lane & 1 ? 0xFFFFu : 0u) | (lane & 2 ? 0xFFFF0000u : 0u);
    unsigned b = (lane & 4 ? 0xFFFFu : 0u) | (lane & 8 ? 0xFFFF0000u : 0u);
    lutm[lane] = (u64)a | ((u64)b << 32);
  }
  __syncthreads();

  // Q fragments: per qi, lane holds q = qt*32 + qi*16 + c, d = 32s+8g+i
  bf16x8 qf[2][2];
#pragma unroll
  for (int qi = 0; qi < 2; ++qi) {
    int q = qt * 32 + qi * 16 + c;
    const float* qrow = qraw + ((size_t)(n * SEQ + q)) * EMB + h * DH;
#pragma unroll
    for (int s = 0; s < 2; ++s) {
      f32x4 x0 = *(const f32x4*)(qrow + 32 * s + 8 * g);
      f32x4 x1 = *(const f32x4*)(qrow + 32 * s + 8 * g + 4);
      bf16x8 t;
#pragma unroll
      for (int i = 0; i < 4; ++i) { t[i] = (bf16)x0[i]; t[4 + i] = (bf16)x1[i]; }
      qf[qi][s] = t;
    }
  }
  const char* kp = (const char*)k2f + (size_t)(n * NH + h) * 32 * 8192 + lane * 16;
  const char* vp = (const char*)vtf + (size_t)(n * NH + h) * 32 * 8192 + lane * 16;
  const u64* mq = mbt + (size_t)n * 32 * 2048 + qt * 32 + c;  // +kt*2048+qi*16

  // K(0) into registers (8 coalesced 1KB chunks)
  bf16x8 K[8], Vv[8];
#pragma unroll
  for (int j = 0; j < 8; ++j) K[j] = *(const bf16x8*)(kp + j * 1024);

  f32x4 oacc[2][4];
#pragma unroll
  for (int qi = 0; qi < 2; ++qi)
#pragma unroll
    for (int dt = 0; dt < 4; ++dt) oacc[qi][dt] = (f32x4){0.f, 0.f, 0.f, 0.f};
  float mrun[2] = {-1e30f, -1e30f}, lrun[2] = {0.f, 0.f};
  bf16x8 ones;
#pragma unroll
  for (int i = 0; i < 8; ++i) ones[i] = (bf16)1.0f;
  int sh0 = 4 * g, sh1 = sh0 + 16;
  int srcA = ((g & 1) << 5) | c;
  int srcB = srcA + 16;
  bool hi2 = (g >> 1) != 0;

  for (int kt = 0; kt < 32; ++kt) {
    // issue V(kt) early — consumed after softmax (~500 cyc later)
#pragma unroll
    for (int j = 0; j < 8; ++j)
      Vv[j] = *(const bf16x8*)(vp + (size_t)kt * 8192 + j * 1024);
    u64 mw0 = mq[kt * 2048];
    u64 mw1 = mq[kt * 2048 + 16];

    // QK^T from K regs: lane(g,c): q=c, kk=16t+4g+r
    f32x4 sacc[2][4];
#pragma unroll
    for (int t = 0; t < 4; ++t) {
      bf16x8 k0 = K[2 * t], k1 = K[2 * t + 1];
#pragma unroll
      for (int qi = 0; qi < 2; ++qi) {
        f32x4 a = {0.f, 0.f, 0.f, 0.f};
        a = mfma16(k0, qf[qi][0], a);
        a = mfma16(k1, qf[qi][1], a);
        sacc[qi][t] = a;
      }
    }
    // prefetch K(kt+1) — K regs free after the MFMAs above; latency hides
    // under softmax+PV (kt=31 reads 8KB past tile 31: valid ws, unused)
#pragma unroll
    for (int j = 0; j < 8; ++j)
      K[j] = *(const bf16x8*)(kp + (size_t)(kt + 1) * 8192 + j * 1024);

    // unmasked row max (max3-friendly triplets), reduce over g via shfl
    float tmax[2];
#pragma unroll
    for (int qi = 0; qi < 2; ++qi) {
      float x0 = sacc[qi][0][0], x1 = sacc[qi][0][1], x2 = sacc[qi][0][2],
            x3 = sacc[qi][0][3], x4 = sacc[qi][1][0], x5 = sacc[qi][1][1],
            x6 = sacc[qi][1][2], x7 = sacc[qi][1][3], x8 = sacc[qi][2][0],
            x9 = sacc[qi][2][1], xa = sacc[qi][2][2], xb = sacc[qi][2][3],
            xc = sacc[qi][3][0], xd = sacc[qi][3][1], xe = sacc[qi][3][2],
            xf = sacc[qi][3][3];
      float t0 = fmaxf(fmaxf(x0, x1), x2);
      float t1 = fmaxf(fmaxf(x3, x4), x5);
      float t2 = fmaxf(fmaxf(x6, x7), x8);
      float t3 = fmaxf(fmaxf(x9, xa), xb);
      float t4 = fmaxf(fmaxf(xc, xd), xe);
      float m = fmaxf(fmaxf(fmaxf(t0, t1), t2), fmaxf(fmaxf(t3, t4), xf));
      m = fmaxf(m, __shfl_xor(m, 16));
      m = fmaxf(m, __shfl_xor(m, 32));
      tmax[qi] = m;
    }
    // defer-max: rescale only when max grew by > 8 (log2 units)
    bool needs = (tmax[0] > mrun[0] + 8.f) || (tmax[1] > mrun[1] + 8.f);
    if (__any(needs)) {
#pragma unroll
      for (int qi = 0; qi < 2; ++qi) {
        float mnew = fmaxf(mrun[qi], tmax[qi]);
        float scl = __builtin_amdgcn_exp2f(mrun[qi] - mnew);
        lrun[qi] *= scl;
#pragma unroll
        for (int dt = 0; dt < 4; ++dt) {
          oacc[qi][dt][0] *= scl; oacc[qi][dt][1] *= scl;
          oacc[qi][dt][2] *= scl; oacc[qi][dt][3] *= scl;
        }
        mrun[qi] = mnew;
      }
    }
    // p = 2^(s-m) in bf16 pairs, mask via LUT-AND
    unsigned wpk[2][4][2];
    u64 mwa[2] = {mw0, mw1};
#pragma unroll
    for (int qi = 0; qi < 2; ++qi) {
      unsigned mlo = (unsigned)mwa[qi], mhi = (unsigned)(mwa[qi] >> 32);
      u64 L[4];
      L[0] = lutm[(mlo >> sh0) & 15];
      L[1] = lutm[(mlo >> sh1) & 15];
      L[2] = lutm[(mhi >> sh0) & 15];
      L[3] = lutm[(mhi >> sh1) & 15];
      float mr = mrun[qi];
#pragma unroll
      for (int t = 0; t < 4; ++t) {
        float p0 = __builtin_amdgcn_exp2f(sacc[qi][t][0] - mr);
        float p1 = __builtin_amdgcn_exp2f(sacc[qi][t][1] - mr);
        float p2 = __builtin_amdgcn_exp2f(sacc[qi][t][2] - mr);
        float p3 = __builtin_amdgcn_exp2f(sacc[qi][t][3] - mr);
        wpk[qi][t][0] = pack_bf16(p0, p1) & (unsigned)L[t];
        wpk[qi][t][1] = pack_bf16(p2, p3) & (unsigned)(L[t] >> 32);
      }
    }
    // P fragments via shuffles (verified): dest lane(g,c) frag s needs
    // kk=32s+8g+i for q=c; sources lanes srcA/srcB, word 2s+(g>>1)
    bf16x8 pf[2][2];
#pragma unroll
    for (int qi = 0; qi < 2; ++qi)
#pragma unroll
      for (int s = 0; s < 2; ++s) {
        unsigned ta0 = (unsigned)__shfl((int)wpk[qi][2 * s][0], srcA);
        unsigned ta1 = (unsigned)__shfl((int)wpk[qi][2 * s][1], srcA);
        unsigned tb0 = (unsigned)__shfl((int)wpk[qi][2 * s + 1][0], srcA);
        unsigned tb1 = (unsigned)__shfl((int)wpk[qi][2 * s + 1][1], srcA);
        unsigned ua0 = (unsigned)__shfl((int)wpk[qi][2 * s][0], srcB);
        unsigned ua1 = (unsigned)__shfl((int)wpk[qi][2 * s][1], srcB);
        unsigned ub0 = (unsigned)__shfl((int)wpk[qi][2 * s + 1][0], srcB);
        unsigned ub1 = (unsigned)__shfl((int)wpk[qi][2 * s + 1][1], srcB);
        u32x4 f;
        f[0] = hi2 ? tb0 : ta0;
        f[1] = hi2 ? tb1 : ta1;
        f[2] = hi2 ? ub0 : ua0;
        f[3] = hi2 ? ub1 : ua1;
        pf[qi][s] = __builtin_bit_cast(bf16x8, f);
      }
    // psum via ones-MFMA on masked P
    f32x4 pacc[2];
#pragma unroll
    for (int qi = 0; qi < 2; ++qi) {
      f32x4 a = {0.f, 0.f, 0.f, 0.f};
      a = mfma16(ones, pf[qi][0], a);
      a = mfma16(ones, pf[qi][1], a);
      pacc[qi] = a;
    }
    // PV from V regs: O^T += V^T · P^T
#pragma unroll
    for (int dt = 0; dt < 4; ++dt)
#pragma unroll
      for (int s = 0; s < 2; ++s) {
        bf16x8 vf = Vv[2 * dt + s];
#pragma unroll
        for (int qi = 0; qi < 2; ++qi)
          oacc[qi][dt] = mfma16(vf, pf[qi][s], oacc[qi][dt]);
      }
#pragma unroll
    for (int qi = 0; qi < 2; ++qi) lrun[qi] += pacc[qi][0];
  }
#pragma unroll
  for (int qi = 0; qi < 2; ++qi) {
    float inv = 1.0f / lrun[qi];
    int q = qt * 32 + qi * 16 + c;
    bf16* orow = a2 + ((size_t)(n * SEQ + q)) * EMB + h * DH;
#pragma unroll
    for (int dt = 0; dt < 4; ++dt) {
      bf16x4 w2;
#pragma unroll
      for (int r = 0; r < 4; ++r) w2[r] = (bf16)(oacc[qi][dt][r] * inv);
      *(bf16x4*)(orow + 16 * dt + 4 * g) = w2;
    }
  }
}

// ---------------- G: out = a2 · Wo2^T + bo (2 et-tiles/block, BK=128) ------
// 64x128 output per block: 32 MFMA per barrier-drain (2x R10), a2 L2
// re-reads halved. 64KB LDS -> 2 blocks/CU (8 waves/CU).
__global__ __launch_bounds__(256) void out_gemm(const bf16* __restrict__ a2,
                                                const bf16* __restrict__ wo2f,
                                                const float* __restrict__ bo,
                                                float* __restrict__ out) {
  int blk = blockIdx.x;  // mt*8 + ep
  int ep = blk & 7, mt = blk >> 3;
  int tid = threadIdx.x, wave = tid >> 6, lane = tid & 63;
  int g = lane >> 4, c = lane & 15;
  int m = mt * 64 + wave * 16 + c;
  const bf16* arow = a2 + (size_t)m * EMB + 8 * g;

  __shared__ bf16 wbuf[2][2][8192];  // [dbuf][et-in-pair][16KB]
  const char* wt0 = (const char*)wo2f + (size_t)(ep * 2) * 32 * 4096;
  const char* wt1 = wt0 + 32 * 4096;
  int lofs = lane * 16, wofs = wave * 1024;

#define STAGEW(J, BUF)                                                        \
  {                                                                           \
    const char* s0_ = wt0 + (size_t)(J) * 16384 + wofs + lofs;                \
    const char* s1_ = wt1 + (size_t)(J) * 16384 + wofs + lofs;                \
    char* d0_ = (char*)&wbuf[BUF][0][0] + wofs;                               \
    char* d1_ = (char*)&wbuf[BUF][1][0] + wofs;                               \
    GL16(s0_, d0_);                                                           \
    GL16(s0_ + 4096, d0_ + 4096);                                             \
    GL16(s0_ + 8192, d0_ + 8192);                                             \
    GL16(s0_ + 12288, d0_ + 12288);                                           \
    GL16(s1_, d1_);                                                           \
    GL16(s1_ + 4096, d1_ + 4096);                                             \
    GL16(s1_ + 8192, d1_ + 8192);                                             \
    GL16(s1_ + 12288, d1_ + 12288);                                           \
  }

  STAGEW(0, 0);
  bf16x8 bn[4];
#pragma unroll
  for (int q = 0; q < 4; ++q) bn[q] = *(const bf16x8*)(arow + q * 32);
  __syncthreads();

  f32x4 acc[2][4];
#pragma unroll
  for (int e2 = 0; e2 < 2; ++e2)
#pragma unroll
    for (int t = 0; t < 4; ++t) acc[e2][t] = (f32x4){0.f, 0.f, 0.f, 0.f};

  for (int j = 0; j < 8; ++j) {
    int cur = j & 1;
    bf16x8 b0 = bn[0], b1 = bn[1], b2 = bn[2], b3 = bn[3];
    if (j < 7) {
      STAGEW(j + 1, cur ^ 1);
#pragma unroll
      for (int q = 0; q < 4; ++q)
        bn[q] = *(const bf16x8*)(arow + (j + 1) * 128 + q * 32);
    }
#pragma unroll
    for (int e2 = 0; e2 < 2; ++e2) {
      const bf16* wb = &wbuf[cur][e2][0];
#pragma unroll
      for (int t = 0; t < 4; ++t)
        acc[e2][t] =
            mfma16(*(const bf16x8*)(wb + t * 512 + lane * 8), b0, acc[e2][t]);
#pragma unroll
      for (int t = 0; t < 4; ++t)
        acc[e2][t] = mfma16(*(const bf16x8*)(wb + 2048 + t * 512 + lane * 8),
                            b1, acc[e2][t]);
#pragma unroll
      for (int t = 0; t < 4; ++t)
        acc[e2][t] = mfma16(*(const bf16x8*)(wb + 4096 + t * 512 + lane * 8),
                            b2, acc[e2][t]);
#pragma unroll
      for (int t = 0; t < 4; ++t)
        acc[e2][t] = mfma16(*(const bf16x8*)(wb + 6144 + t * 512 + lane * 8),
                            b3, acc[e2][t]);
    }
    __syncthreads();
  }
#pragma unroll
  for (int e2 = 0; e2 < 2; ++e2)
#pragma unroll
    for (int t = 0; t < 4; ++t) {
      int e = (ep * 2 + e2) * 64 + 16 * t + 4 * g;
      f32x4 b = *(const f32x4*)(bo + e);
      f32x4 w;
#pragma unroll
      for (int r = 0; r < 4; ++r) w[r] = acc[e2][t][r] + b[r];
      *(f32x4*)(out + (size_t)m * EMB + e) = w;
    }
}

extern "C" void kernel_launch(void* const* d_in, const int* in_sizes, int n_in,
                              void* d_out, int out_size, void* d_ws, size_t ws_size,
                              hipStream_t stream) {
  const float* values = (const float*)d_in[0];
  const float* keys   = (const float*)d_in[1];
  const float* query  = (const float*)d_in[2];
  const int*   mask   = (const int*)d_in[3];
  const float* Wv     = (const float*)d_in[4];
  const float* Wk     = (const float*)d_in[5];
  const float* Wq     = (const float*)d_in[6];
  const float* Wo     = (const float*)d_in[7];
  const float* bo     = (const float*)d_in[8];

  char* ws = (char*)d_ws;
  bf16* mqk  = (bf16*)(ws + OFF_MQK);
  bf16* wo2f = (bf16*)(ws + OFF_WO2);
  bf16* k2f  = (bf16*)(ws + OFF_K2);
  bf16* vtf  = (bf16*)(ws + OFF_VT);
  bf16* a2   = (bf16*)(ws + OFF_A2);
  u64*  mbt  = (u64*)(ws + OFF_MB);

  prep0<<<16, 256, 0, stream>>>(Wq, Wk, mqk);
  prep_fused<<<4352, 256, 0, stream>>>(Wo, Wv, keys, mqk, values, mask,
                                       wo2f, k2f, vtf, mbt);
  attn<<<2048, 64, 0, stream>>>(query, k2f, vtf, mbt, a2);
  out_gemm<<<512, 256, 0, stream>>>(a2, wo2f, bo, (float*)d_out);
}